// Round 6
// baseline (137.529 us; speedup 1.0000x reference)
//
#include <hip/hip_runtime.h>
#include <hip/hip_bf16.h>
#include <math.h>

#define NN 4096
#define DD 1024
#define NCLS 128
#define TAU 0.5f
#define EPSV 1e-8f
#define NB_GEMM 2080   // 64*65/2 upper-triangle 64x64 tiles; 2080 = 8 XCDs * 260

typedef __bf16 bf16;
typedef __bf16 bf16x8 __attribute__((ext_vector_type(8)));
typedef __bf16 bf16x4 __attribute__((ext_vector_type(4)));
typedef float f32x4 __attribute__((ext_vector_type(4)));

__device__ __forceinline__ void gl2lds16(const void* g, void* l) {
    __builtin_amdgcn_global_load_lds(
        (const __attribute__((address_space(1))) void*)g,
        (__attribute__((address_space(3))) void*)l,
        16, 0, 0);
}

// K1: block 0 = class stats -> per-row first-pos index fpos[i];
//     blocks 1..NN/4 = per-row L2 norm -> normalized bf16 copy, zero rowsum/posv.
__global__ __launch_bounds__(256) void k_prep(const float* __restrict__ X,
                                              const int* __restrict__ y,
                                              bf16* __restrict__ Xn,
                                              float* __restrict__ rsum,
                                              float* __restrict__ posv,
                                              int* __restrict__ cnt,
                                              int* __restrict__ fpos) {
    const int t = threadIdx.x;
    if (blockIdx.x == 0) {
        __shared__ int sc[NCLS], s1[NCLS], s2[NCLS];
        if (t < NCLS) { sc[t] = 0; s1[t] = 0x7fffffff; s2[t] = 0x7fffffff; }
        __syncthreads();
        int yv[16];
#pragma unroll
        for (int k = 0; k < 16; ++k) {
            int i = t + k * 256;
            yv[k] = y[i];
            atomicAdd(&sc[yv[k]], 1);
            atomicMin(&s1[yv[k]], i);
        }
        __syncthreads();
#pragma unroll
        for (int k = 0; k < 16; ++k) {
            int i = t + k * 256;
            if (s1[yv[k]] != i) atomicMin(&s2[yv[k]], i);
        }
        __syncthreads();
#pragma unroll
        for (int k = 0; k < 16; ++k) {
            int i = t + k * 256;
            int c = yv[k];
            fpos[i] = (sc[c] >= 2) ? (s1[c] == i ? s2[c] : s1[c]) : -1;
        }
        if (t < NCLS) cnt[t] = sc[t];
        return;
    }
    const int w = t >> 6, lane = t & 63;
    const int row = (blockIdx.x - 1) * 4 + w;
    const float* xr = X + (size_t)row * DD;
    float4 v[4];
    float ss = 0.f;
#pragma unroll
    for (int c = 0; c < 4; ++c) {
        v[c] = *(const float4*)(xr + c * 256 + lane * 4);
        ss += v[c].x * v[c].x + v[c].y * v[c].y + v[c].z * v[c].z + v[c].w * v[c].w;
    }
#pragma unroll
    for (int m = 1; m < 64; m <<= 1) ss += __shfl_xor(ss, m, 64);
    float rn = 1.f / fmaxf(sqrtf(ss), EPSV);
    if (lane == 0) { rsum[row] = 0.f; posv[row] = 0.f; }
#pragma unroll
    for (int c = 0; c < 4; ++c) {
        bf16x4 o;
        o.x = (bf16)(v[c].x * rn);
        o.y = (bf16)(v[c].y * rn);
        o.z = (bf16)(v[c].z * rn);
        o.w = (bf16)(v[c].w * rn);
        *(bf16x4*)(Xn + (size_t)row * DD + c * 256 + lane * 4) = o;
    }
}

// K2: upper-triangle 64x64-tile bf16 MFMA gram with fused exp/mask epilogue,
// row+col rowsum reduction (symmetry), posv extraction.
// Round-5 diagnosis: the 128^2 grid (528 blocks = 2.06/CU, 3 dispatch rounds)
// is latency-bound at 2 blocks/CU — no TLP, and explicit pipelining regressed
// (m131-m141 reproduced). Fix: re-grid to the TLP regime. 64^2 tiles -> 2080
// blocks (8.1/CU), 4 waves/block, 16.4 KB LDS, ~40 VGPR -> 8 blocks/CU (32
// waves): implicit wave-overlap hides staging (m114), no asm scheduling.
// NO device-scope fences (round-1 lesson: per-block L2 wb/inv -> 93us).
__global__ __launch_bounds__(256) void k_gemm(const bf16* __restrict__ Xn,
                                              const int* __restrict__ y,
                                              const int* __restrict__ fpos,
                                              float* __restrict__ rowsum,
                                              float* __restrict__ posv) {
    __shared__ __align__(16) bf16 As[2][64 * 32];   // 2 x 4 KB
    __shared__ __align__(16) bf16 Bs[2][64 * 32];   // 2 x 4 KB

    // bijective XCD swizzle: 2080 = 8 * 260
    int id = (blockIdx.x & 7) * 260 + (blockIdx.x >> 3);
    // decode linear id -> (bi, bj), bi <= bj
    float ff = sqrtf((float)(8 * id + 1));
    int bj = (int)((ff - 1.f) * 0.5f);
    if (bj * (bj + 1) / 2 > id) bj--;
    if ((bj + 1) * (bj + 2) / 2 <= id) bj++;
    int bi = id - bj * (bj + 1) / 2;
    const int rowA0 = bi * 64;
    const int rowB0 = bj * 64;
    const bool diag = (bi == bj);

    const int tid = threadIdx.x;
    const int lane = tid & 63;
    const int w = tid >> 6;              // 0..3
    const int wm = w & 1, wn = w >> 1;   // 2x2 waves: wave owns 32 rows x 32 cols
    const int lr = lane >> 4, lc = lane & 15;

    f32x4 acc[2][2];
#pragma unroll
    for (int i = 0; i < 2; ++i)
#pragma unroll
        for (int j = 0; j < 2; ++j) acc[i][j] = (f32x4){0.f, 0.f, 0.f, 0.f};

    // staging with k-slot XOR swizzle: slot g of row r holds k-group g^((r>>1)&3)
    const int r = tid >> 2;              // 0..63 (256 threads cover 64-row tile)
    const int g = tid & 3;
    const int kg = g ^ ((r >> 1) & 3);
    const bf16* gA = Xn + (size_t)(rowA0 + r) * DD + kg * 8;
    const bf16* gB = Xn + (size_t)(rowB0 + r) * DD + kg * 8;
    const int loff = tid * 8;

    const int sw = (lc >> 1) & 3;   // read-side swizzle inverse

    // prologue: stage k0=0 into buf 0
    gl2lds16(gA, &As[0][loff]);
    gl2lds16(gB, &Bs[0][loff]);
    __syncthreads();

    int cur = 0;
    for (int k0 = 0; k0 < DD; k0 += 32) {
        if (k0 + 32 < DD) {             // issue next tile's loads EARLY
            gl2lds16(gA + k0 + 32, &As[cur ^ 1][loff]);
            gl2lds16(gB + k0 + 32, &Bs[cur ^ 1][loff]);
        }
        bf16x8 af[2], bfr[2];
#pragma unroll
        for (int mt = 0; mt < 2; ++mt)
            af[mt] = *(const bf16x8*)(&As[cur][(wm * 32 + mt * 16 + lc) * 32 + ((lr ^ sw) * 8)]);
#pragma unroll
        for (int nt = 0; nt < 2; ++nt)
            bfr[nt] = *(const bf16x8*)(&Bs[cur][(wn * 32 + nt * 16 + lc) * 32 + ((lr ^ sw) * 8)]);
#pragma unroll
        for (int mt = 0; mt < 2; ++mt)
#pragma unroll
            for (int nt = 0; nt < 2; ++nt)
                acc[mt][nt] = __builtin_amdgcn_mfma_f32_16x16x32_bf16(
                    af[mt], bfr[nt], acc[mt][nt], 0, 0, 0);
        __syncthreads();                // drains staged loads; buf swap safe
        cur ^= 1;
    }

    // Epilogue: S=(c+1)*0.25; mask same-class (incl. diagonal); row+col exp-sums;
    // posv where (row,col) hits an (i, fp(i)) pair. y/fpos read direct (L1/L2-hot).
    int cloc[2], ycol[2], fcol[2];
    bool pcol[2];
#pragma unroll
    for (int nt = 0; nt < 2; ++nt) {
        cloc[nt] = wn * 32 + nt * 16 + lc;
        ycol[nt] = y[rowB0 + cloc[nt]];
        fcol[nt] = fpos[rowB0 + cloc[nt]];
        pcol[nt] = ((unsigned)(fcol[nt] - rowA0) < 64u);
    }
    float colacc[2] = {0.f, 0.f};
#pragma unroll
    for (int mt = 0; mt < 2; ++mt) {
#pragma unroll
        for (int rr = 0; rr < 4; ++rr) {
            int rloc = wm * 32 + mt * 16 + lr * 4 + rr;  // C row = (lane>>4)*4+reg
            int rglob = rowA0 + rloc;
            int yrow = y[rglob];
            int fprow = fpos[rglob];
            bool prow = ((unsigned)(fprow - rowB0) < 64u);
            float s = 0.f;
#pragma unroll
            for (int nt = 0; nt < 2; ++nt) {
                float Sv = (acc[mt][nt][rr] + 1.f) * (0.5f * TAU);
                int cg = rowB0 + cloc[nt];
                if (prow && cg == fprow) posv[rglob] = Sv;
                if (pcol[nt] && fcol[nt] == rglob) posv[cg] = Sv;
                float e = (ycol[nt] != yrow) ? __expf(Sv) : 0.f;
                s += e;
                colacc[nt] += e;
            }
            s += __shfl_xor(s, 1, 16);
            s += __shfl_xor(s, 2, 16);
            s += __shfl_xor(s, 4, 16);
            s += __shfl_xor(s, 8, 16);
            if (lc == 0) atomicAdd(&rowsum[rglob], s);
        }
    }
    if (!diag) {
#pragma unroll
        for (int nt = 0; nt < 2; ++nt) {
            float cs = colacc[nt];
            cs += __shfl_xor(cs, 16, 64);
            cs += __shfl_xor(cs, 32, 64);
            if (lane < 16) atomicAdd(&rowsum[rowB0 + wn * 32 + nt * 16 + lane], cs);
        }
    }
}

// K3: single block; lse_i = log(rowsum_i + exp(pv_i) + (N-2+cnt)); out = mean(lse - pv)
__global__ __launch_bounds__(1024) void k_finalize(const float* __restrict__ rowsum,
                                                   const float* __restrict__ posv,
                                                   const int* __restrict__ y,
                                                   const int* __restrict__ cnt,
                                                   float* __restrict__ out) {
    int t = threadIdx.x;
    float acc = 0.f;
#pragma unroll
    for (int k = 0; k < 4; ++k) {
        int i = t + k * 1024;
        float pv = posv[i];
        float tot = rowsum[i] + __expf(pv) + (float)(NN - 2 + cnt[y[i]]);
        acc += logf(tot) - pv;
    }
#pragma unroll
    for (int m = 1; m < 64; m <<= 1) acc += __shfl_xor(acc, m, 64);
    __shared__ float wsum[16];
    int w = t >> 6, lane = t & 63;
    if (lane == 0) wsum[w] = acc;
    __syncthreads();
    if (t == 0) {
        float s = 0.f;
#pragma unroll
        for (int q = 0; q < 16; ++q) s += wsum[q];
        *out = s / (float)NN;
    }
}

extern "C" void kernel_launch(void* const* d_in, const int* in_sizes, int n_in,
                              void* d_out, int out_size, void* d_ws, size_t ws_size,
                              hipStream_t stream) {
    const float* X = (const float*)d_in[0];
    const int* y = (const int*)d_in[1];
    float* out = (float*)d_out;

    char* ws = (char*)d_ws;
    bf16* Xn    = (bf16*)ws;                                   // 8 MB
    float* rsum = (float*)(ws + 8 * 1024 * 1024);              // 16 KB
    float* posv = (float*)(ws + 8 * 1024 * 1024 + 16 * 1024);  // 16 KB
    int* cnt    = (int*)(ws + 8 * 1024 * 1024 + 32 * 1024);    // 512 B
    int* fpos   = (int*)(ws + 8 * 1024 * 1024 + 36 * 1024);    // 16 KB

    k_prep<<<dim3(NN / 4 + 1), 256, 0, stream>>>(X, y, Xn, rsum, posv, cnt, fpos);
    k_gemm<<<dim3(NB_GEMM), 256, 0, stream>>>(Xn, y, fpos, rsum, posv);
    k_finalize<<<dim3(1), 1024, 0, stream>>>(rsum, posv, y, cnt, out);
}

// Round 7
// 136.994 us; speedup vs baseline: 1.0039x; 1.0039x over previous
//
#include <hip/hip_runtime.h>
#include <hip/hip_bf16.h>
#include <math.h>

#define NN 4096
#define DD 1024
#define NCLS 128
#define TAU 0.5f
#define EPSV 1e-8f
#define NB_GEMM 1056   // 128x64 tiles covering upper triangle: sum(64-2bi)=1056 = 8*132

typedef __bf16 bf16;
typedef __bf16 bf16x8 __attribute__((ext_vector_type(8)));
typedef __bf16 bf16x4 __attribute__((ext_vector_type(4)));
typedef float f32x4 __attribute__((ext_vector_type(4)));

__device__ __forceinline__ void gl2lds16(const void* g, void* l) {
    __builtin_amdgcn_global_load_lds(
        (const __attribute__((address_space(1))) void*)g,
        (__attribute__((address_space(3))) void*)l,
        16, 0, 0);
}

// K1: block 0 = class stats -> per-row first-pos index fpos[i];
//     blocks 1..NN/4 = per-row L2 norm -> normalized bf16 copy, zero rowsum/posv.
__global__ __launch_bounds__(256) void k_prep(const float* __restrict__ X,
                                              const int* __restrict__ y,
                                              bf16* __restrict__ Xn,
                                              float* __restrict__ rsum,
                                              float* __restrict__ posv,
                                              int* __restrict__ cnt,
                                              int* __restrict__ fpos) {
    const int t = threadIdx.x;
    if (blockIdx.x == 0) {
        __shared__ int sc[NCLS], s1[NCLS], s2[NCLS];
        if (t < NCLS) { sc[t] = 0; s1[t] = 0x7fffffff; s2[t] = 0x7fffffff; }
        __syncthreads();
        int yv[16];
#pragma unroll
        for (int k = 0; k < 16; ++k) {
            int i = t + k * 256;
            yv[k] = y[i];
            atomicAdd(&sc[yv[k]], 1);
            atomicMin(&s1[yv[k]], i);
        }
        __syncthreads();
#pragma unroll
        for (int k = 0; k < 16; ++k) {
            int i = t + k * 256;
            if (s1[yv[k]] != i) atomicMin(&s2[yv[k]], i);
        }
        __syncthreads();
#pragma unroll
        for (int k = 0; k < 16; ++k) {
            int i = t + k * 256;
            int c = yv[k];
            fpos[i] = (sc[c] >= 2) ? (s1[c] == i ? s2[c] : s1[c]) : -1;
        }
        if (t < NCLS) cnt[t] = sc[t];
        return;
    }
    const int w = t >> 6, lane = t & 63;
    const int row = (blockIdx.x - 1) * 4 + w;
    const float* xr = X + (size_t)row * DD;
    float4 v[4];
    float ss = 0.f;
#pragma unroll
    for (int c = 0; c < 4; ++c) {
        v[c] = *(const float4*)(xr + c * 256 + lane * 4);
        ss += v[c].x * v[c].x + v[c].y * v[c].y + v[c].z * v[c].z + v[c].w * v[c].w;
    }
#pragma unroll
    for (int m = 1; m < 64; m <<= 1) ss += __shfl_xor(ss, m, 64);
    float rn = 1.f / fmaxf(sqrtf(ss), EPSV);
    if (lane == 0) { rsum[row] = 0.f; posv[row] = 0.f; }
#pragma unroll
    for (int c = 0; c < 4; ++c) {
        bf16x4 o;
        o.x = (bf16)(v[c].x * rn);
        o.y = (bf16)(v[c].y * rn);
        o.z = (bf16)(v[c].z * rn);
        o.w = (bf16)(v[c].w * rn);
        *(bf16x4*)(Xn + (size_t)row * DD + c * 256 + lane * 4) = o;
    }
}

// K2: 128x64-tile bf16 MFMA gram over the upper triangle, fused exp/mask
// epilogue with row+col rowsum reduction and posv extraction.
// R6 lesson: perf tracks (blocks>=1024) AND (>=8 MFMA/wave/step), not
// occupancy. 128x64 rect tiles give 1056 blocks (4.1/CU) at R4's proven wave
// shape (4 waves, 64x32 out, acc[4][2]). Diagonal-straddle tiles are handled
// by a uniform (row < col) mask on the exp term: each unordered pair is
// covered exactly once, so the col-reduce is unconditional.
// NO device-scope fences (round-1 lesson: per-block L2 wb/inv -> 93us).
__global__ __launch_bounds__(256) void k_gemm(const bf16* __restrict__ Xn,
                                              const int* __restrict__ y,
                                              const int* __restrict__ fpos,
                                              float* __restrict__ rowsum,
                                              float* __restrict__ posv) {
    __shared__ __align__(16) bf16 As[2][128 * 32];   // 2 x 8 KB
    __shared__ __align__(16) bf16 Bs[2][64 * 32];    // 2 x 4 KB   (24 KB total)

    // bijective XCD swizzle: 1056 = 8 * 132
    int id = (blockIdx.x & 7) * 132 + (blockIdx.x >> 3);
    // decode: bi in 0..31 (128-row strip), bj in 2bi..63 (64-col strip).
    // cumulative C(bi) = bi*(65-bi)
    int bi = (int)((65.f - sqrtf((float)(4225 - 4 * id))) * 0.5f);
    while (bi * (65 - bi) > id) bi--;
    while ((bi + 1) * (64 - bi) <= id) bi++;
    int bj = 2 * bi + (id - bi * (65 - bi));
    const int rowA0 = bi * 128;
    const int rowB0 = bj * 64;

    const int tid = threadIdx.x;
    const int lane = tid & 63;
    const int w = tid >> 6;              // 0..3
    const int wm = w & 1, wn = w >> 1;   // wave owns 64 rows x 32 cols
    const int lr = lane >> 4, lc = lane & 15;

    f32x4 acc[4][2];
#pragma unroll
    for (int i = 0; i < 4; ++i)
#pragma unroll
        for (int j = 0; j < 2; ++j) acc[i][j] = (f32x4){0.f, 0.f, 0.f, 0.f};

    // staging with k-slot XOR swizzle: slot g of row r holds k-group g^((r>>1)&3)
    // (rows r and r+64 share the same swizzle since 64>>1 == 32 ≡ 0 mod 4)
    const int r = tid >> 2;              // 0..63
    const int g = tid & 3;
    const int kg = g ^ ((r >> 1) & 3);
    const bf16* gA0 = Xn + (size_t)(rowA0 + r) * DD + kg * 8;
    const bf16* gA1 = gA0 + (size_t)64 * DD;
    const bf16* gB  = Xn + (size_t)(rowB0 + r) * DD + kg * 8;
    const int loff = tid * 8;

    const int sw = (lc >> 1) & 3;   // read-side swizzle inverse

    // prologue: stage k0=0 into buf 0
    gl2lds16(gA0, &As[0][loff]);
    gl2lds16(gA1, &As[0][2048 + loff]);
    gl2lds16(gB,  &Bs[0][loff]);
    __syncthreads();

    int cur = 0;
    for (int k0 = 0; k0 < DD; k0 += 32) {
        if (k0 + 32 < DD) {             // issue next tile's loads EARLY
            gl2lds16(gA0 + k0 + 32, &As[cur ^ 1][loff]);
            gl2lds16(gA1 + k0 + 32, &As[cur ^ 1][2048 + loff]);
            gl2lds16(gB  + k0 + 32, &Bs[cur ^ 1][loff]);
        }
        bf16x8 af[4], bfr[2];
#pragma unroll
        for (int mt = 0; mt < 4; ++mt)
            af[mt] = *(const bf16x8*)(&As[cur][(wm * 64 + mt * 16 + lc) * 32 + ((lr ^ sw) * 8)]);
#pragma unroll
        for (int nt = 0; nt < 2; ++nt)
            bfr[nt] = *(const bf16x8*)(&Bs[cur][(wn * 32 + nt * 16 + lc) * 32 + ((lr ^ sw) * 8)]);
#pragma unroll
        for (int mt = 0; mt < 4; ++mt)
#pragma unroll
            for (int nt = 0; nt < 2; ++nt)
                acc[mt][nt] = __builtin_amdgcn_mfma_f32_16x16x32_bf16(
                    af[mt], bfr[nt], acc[mt][nt], 0, 0, 0);
        __syncthreads();                // drains staged loads; buf swap safe
        cur ^= 1;
    }

    // Epilogue: S=(c+1)*0.25; contribute only cells with row<col AND class
    // differs (covers diagonal + below-diagonal cells of straddle tiles);
    // row-reduce + unconditional col-reduce; posv where (row,col)=(i,fp(i)).
    int cloc[2], ycol[2], fcol[2];
    bool pcol[2];
#pragma unroll
    for (int nt = 0; nt < 2; ++nt) {
        cloc[nt] = wn * 32 + nt * 16 + lc;
        ycol[nt] = y[rowB0 + cloc[nt]];
        fcol[nt] = fpos[rowB0 + cloc[nt]];
        pcol[nt] = ((unsigned)(fcol[nt] - rowA0) < 128u);
    }
    float colacc[2] = {0.f, 0.f};
#pragma unroll
    for (int mt = 0; mt < 4; ++mt) {
#pragma unroll
        for (int rr = 0; rr < 4; ++rr) {
            int rloc = wm * 64 + mt * 16 + lr * 4 + rr;  // C row = (lane>>4)*4+reg
            int rglob = rowA0 + rloc;
            int yrow = y[rglob];
            int fprow = fpos[rglob];
            bool prow = ((unsigned)(fprow - rowB0) < 64u);
            float s = 0.f;
#pragma unroll
            for (int nt = 0; nt < 2; ++nt) {
                float Sv = (acc[mt][nt][rr] + 1.f) * (0.5f * TAU);
                int cg = rowB0 + cloc[nt];
                if (prow && cg == fprow) posv[rglob] = Sv;
                if (pcol[nt] && fcol[nt] == rglob) posv[cg] = Sv;
                float e = (ycol[nt] != yrow && rglob < cg) ? __expf(Sv) : 0.f;
                s += e;
                colacc[nt] += e;
            }
            s += __shfl_xor(s, 1, 16);
            s += __shfl_xor(s, 2, 16);
            s += __shfl_xor(s, 4, 16);
            s += __shfl_xor(s, 8, 16);
            if (lc == 0) atomicAdd(&rowsum[rglob], s);
        }
    }
#pragma unroll
    for (int nt = 0; nt < 2; ++nt) {
        float cs = colacc[nt];
        cs += __shfl_xor(cs, 16, 64);
        cs += __shfl_xor(cs, 32, 64);
        if (lane < 16) atomicAdd(&rowsum[rowB0 + wn * 32 + nt * 16 + lane], cs);
    }
}

// K3: single block; lse_i = log(rowsum_i + exp(pv_i) + (N-2+cnt)); out = mean(lse - pv)
__global__ __launch_bounds__(1024) void k_finalize(const float* __restrict__ rowsum,
                                                   const float* __restrict__ posv,
                                                   const int* __restrict__ y,
                                                   const int* __restrict__ cnt,
                                                   float* __restrict__ out) {
    int t = threadIdx.x;
    float acc = 0.f;
#pragma unroll
    for (int k = 0; k < 4; ++k) {
        int i = t + k * 1024;
        float pv = posv[i];
        float tot = rowsum[i] + __expf(pv) + (float)(NN - 2 + cnt[y[i]]);
        acc += logf(tot) - pv;
    }
#pragma unroll
    for (int m = 1; m < 64; m <<= 1) acc += __shfl_xor(acc, m, 64);
    __shared__ float wsum[16];
    int w = t >> 6, lane = t & 63;
    if (lane == 0) wsum[w] = acc;
    __syncthreads();
    if (t == 0) {
        float s = 0.f;
#pragma unroll
        for (int q = 0; q < 16; ++q) s += wsum[q];
        *out = s / (float)NN;
    }
}

extern "C" void kernel_launch(void* const* d_in, const int* in_sizes, int n_in,
                              void* d_out, int out_size, void* d_ws, size_t ws_size,
                              hipStream_t stream) {
    const float* X = (const float*)d_in[0];
    const int* y = (const int*)d_in[1];
    float* out = (float*)d_out;

    char* ws = (char*)d_ws;
    bf16* Xn    = (bf16*)ws;                                   // 8 MB
    float* rsum = (float*)(ws + 8 * 1024 * 1024);              // 16 KB
    float* posv = (float*)(ws + 8 * 1024 * 1024 + 16 * 1024);  // 16 KB
    int* cnt    = (int*)(ws + 8 * 1024 * 1024 + 32 * 1024);    // 512 B
    int* fpos   = (int*)(ws + 8 * 1024 * 1024 + 36 * 1024);    // 16 KB

    k_prep<<<dim3(NN / 4 + 1), 256, 0, stream>>>(X, y, Xn, rsum, posv, cnt, fpos);
    k_gemm<<<dim3(NB_GEMM), 256, 0, stream>>>(Xn, y, fpos, rsum, posv);
    k_finalize<<<dim3(1), 1024, 0, stream>>>(rsum, posv, y, cnt, out);
}

// Round 8
// 126.337 us; speedup vs baseline: 1.0886x; 1.0844x over previous
//
#include <hip/hip_runtime.h>
#include <hip/hip_bf16.h>
#include <math.h>

#define NN 4096
#define DD 1024
#define NCLS 128
#define TAU 0.5f
#define EPSV 1e-8f
#define NB_GEMM 256   // full-square 16x16 grid of 256x256 tiles = 1 block/CU
#define NT 32         // K-steps (DD / 32)

typedef __bf16 bf16;
typedef __bf16 bf16x8 __attribute__((ext_vector_type(8)));
typedef __bf16 bf16x4 __attribute__((ext_vector_type(4)));
typedef float f32x4 __attribute__((ext_vector_type(4)));

__device__ __forceinline__ void gl2lds16(const void* g, void* l) {
    __builtin_amdgcn_global_load_lds(
        (const __attribute__((address_space(1))) void*)g,
        (__attribute__((address_space(3))) void*)l,
        16, 0, 0);
}

// K1: block 0 = class stats -> per-row first-pos index fpos[i];
//     blocks 1..NN/4 = per-row L2 norm -> normalized bf16 copy, zero rowsum/posv.
__global__ __launch_bounds__(256) void k_prep(const float* __restrict__ X,
                                              const int* __restrict__ y,
                                              bf16* __restrict__ Xn,
                                              float* __restrict__ rsum,
                                              float* __restrict__ posv,
                                              int* __restrict__ cnt,
                                              int* __restrict__ fpos) {
    const int t = threadIdx.x;
    if (blockIdx.x == 0) {
        __shared__ int sc[NCLS], s1[NCLS], s2[NCLS];
        if (t < NCLS) { sc[t] = 0; s1[t] = 0x7fffffff; s2[t] = 0x7fffffff; }
        __syncthreads();
        int yv[16];
#pragma unroll
        for (int k = 0; k < 16; ++k) {
            int i = t + k * 256;
            yv[k] = y[i];
            atomicAdd(&sc[yv[k]], 1);
            atomicMin(&s1[yv[k]], i);
        }
        __syncthreads();
#pragma unroll
        for (int k = 0; k < 16; ++k) {
            int i = t + k * 256;
            if (s1[yv[k]] != i) atomicMin(&s2[yv[k]], i);
        }
        __syncthreads();
#pragma unroll
        for (int k = 0; k < 16; ++k) {
            int i = t + k * 256;
            int c = yv[k];
            fpos[i] = (sc[c] >= 2) ? (s1[c] == i ? s2[c] : s1[c]) : -1;
        }
        if (t < NCLS) cnt[t] = sc[t];
        return;
    }
    const int w = t >> 6, lane = t & 63;
    const int row = (blockIdx.x - 1) * 4 + w;
    const float* xr = X + (size_t)row * DD;
    float4 v[4];
    float ss = 0.f;
#pragma unroll
    for (int c = 0; c < 4; ++c) {
        v[c] = *(const float4*)(xr + c * 256 + lane * 4);
        ss += v[c].x * v[c].x + v[c].y * v[c].y + v[c].z * v[c].z + v[c].w * v[c].w;
    }
#pragma unroll
    for (int m = 1; m < 64; m <<= 1) ss += __shfl_xor(ss, m, 64);
    float rn = 1.f / fmaxf(sqrtf(ss), EPSV);
    if (lane == 0) { rsum[row] = 0.f; posv[row] = 0.f; }
#pragma unroll
    for (int c = 0; c < 4; ++c) {
        bf16x4 o;
        o.x = (bf16)(v[c].x * rn);
        o.y = (bf16)(v[c].y * rn);
        o.z = (bf16)(v[c].z * rn);
        o.w = (bf16)(v[c].w * rn);
        *(bf16x4*)(Xn + (size_t)row * DD + c * 256 + lane * 4) = o;
    }
}

// K2: FULL-SQUARE 256x256-tile bf16 MFMA gram, m201-style counted-vmcnt
// schedule (T3+T4+T5) for the 1-block/CU regime.
// R3-R7 lesson: the 2-barrier structure's stage+drain is ~72% of critical path
// at any grid size (m233 reproduced); counted vmcnt(4) keeps next tile's loads
// in flight across barriers, never draining to 0 until the peeled last step.
// Full square (2x FLOP) is free: triangle would idle 120 CUs at this tile size,
// and it simplifies the epilogue to row-side only (diagonal auto-masked by
// same-class; every (i,j) covered exactly once).
// NO device-scope fences (round-1 lesson: per-block L2 wb/inv -> 93us).
__global__ __launch_bounds__(512, 2) void k_gemm(const bf16* __restrict__ Xn,
                                                 const int* __restrict__ y,
                                                 const int* __restrict__ fpos,
                                                 float* __restrict__ rowsum,
                                                 float* __restrict__ posv) {
    __shared__ __align__(16) bf16 As[2][256 * 32];   // 2 x 16 KB
    __shared__ __align__(16) bf16 Bs[2][256 * 32];   // 2 x 16 KB -> 64 KB total

    // bijective XCD swizzle: 256 = 8 * 32 (each XCD gets 2 full block-rows)
    const int id = (blockIdx.x & 7) * 32 + (blockIdx.x >> 3);
    const int rowA0 = (id >> 4) * 256;   // row strip
    const int rowB0 = (id & 15) * 256;   // col strip

    const int tid = threadIdx.x;
    const int lane = tid & 63;
    const int w = tid >> 6;              // 0..7
    const int wm = w & 1, wn = w >> 1;   // 2x4 waves: wave owns 128 rows x 64 cols
    const int lr = lane >> 4, lc = lane & 15;
    const int sw = (lc >> 1) & 3;        // read-side k-slot swizzle inverse

    f32x4 acc[8][4];
#pragma unroll
    for (int i = 0; i < 8; ++i)
#pragma unroll
        for (int j = 0; j < 4; ++j) acc[i][j] = (f32x4){0.f, 0.f, 0.f, 0.f};

    // staging: thread covers row r and r+128 of both A and B strips.
    // k-slot XOR swizzle: slot g of row r holds k-group g^((r>>1)&3).
    const int r = tid >> 2;              // 0..127
    const int g = tid & 3;
    const int kg = g ^ ((r >> 1) & 3);
    const bf16* gA0 = Xn + (size_t)(rowA0 + r) * DD + kg * 8;
    const bf16* gA1 = gA0 + (size_t)128 * DD;
    const bf16* gB0 = Xn + (size_t)(rowB0 + r) * DD + kg * 8;
    const bf16* gB1 = gB0 + (size_t)128 * DD;
    const int loff = tid * 8;            // elem offset = r*32 + g*8

    auto stage = [&](int buf, int k0) {
        gl2lds16(gA0 + k0, &As[buf][loff]);
        gl2lds16(gA1 + k0, &As[buf][4096 + loff]);
        gl2lds16(gB0 + k0, &Bs[buf][loff]);
        gl2lds16(gB1 + k0, &Bs[buf][4096 + loff]);
    };
    auto compute = [&](int buf) {
        bf16x8 af[8], bfr[4];
#pragma unroll
        for (int mt = 0; mt < 8; ++mt)
            af[mt] = *(const bf16x8*)(&As[buf][(wm * 128 + mt * 16 + lc) * 32 + ((lr ^ sw) * 8)]);
#pragma unroll
        for (int nt = 0; nt < 4; ++nt)
            bfr[nt] = *(const bf16x8*)(&Bs[buf][(wn * 64 + nt * 16 + lc) * 32 + ((lr ^ sw) * 8)]);
        __builtin_amdgcn_s_setprio(1);
#pragma unroll
        for (int mt = 0; mt < 8; ++mt)
#pragma unroll
            for (int nt = 0; nt < 4; ++nt)
                acc[mt][nt] = __builtin_amdgcn_mfma_f32_16x16x32_bf16(
                    af[mt], bfr[nt], acc[mt][nt], 0, 0, 0);
        __builtin_amdgcn_s_setprio(0);
    };

    // prologue: stage tile 0
    stage(0, 0);

    // main loop t=0..30: stage t+1, wait ONLY tile t's loads (vmcnt(4) = allow
    // t+1's 4 to stay in flight), barrier, compute t, release buffer.
#pragma unroll 2
    for (int t = 0; t < NT - 1; ++t) {
        const int cur = t & 1;
        stage(cur ^ 1, (t + 1) * 32);
        asm volatile("s_waitcnt vmcnt(4)" ::: "memory");
        __builtin_amdgcn_s_barrier();
        compute(cur);
        asm volatile("s_waitcnt lgkmcnt(0)" ::: "memory");
        __builtin_amdgcn_s_barrier();
    }
    // peeled last step: nothing left to stage -> full drain is correct here
    asm volatile("s_waitcnt vmcnt(0)" ::: "memory");
    __builtin_amdgcn_s_barrier();
    compute((NT - 1) & 1);

    // Epilogue (row-side only): S=(c+1)*0.25; mask same-class (diag included
    // automatically); per-row exp-sum over this block's 256 cols via 4 nt-regs
    // + 16-lane shuffle; posv where (row,col)=(i,fp(i)).
    int ycol[4], cloc[4];
#pragma unroll
    for (int nt = 0; nt < 4; ++nt) {
        cloc[nt] = wn * 64 + nt * 16 + lc;
        ycol[nt] = y[rowB0 + cloc[nt]];
    }
#pragma unroll
    for (int mt = 0; mt < 8; ++mt) {
#pragma unroll
        for (int rr = 0; rr < 4; ++rr) {
            int rloc = wm * 128 + mt * 16 + lr * 4 + rr;  // C row = (lane>>4)*4+reg
            int rglob = rowA0 + rloc;
            int yrow = y[rglob];
            int fprow = fpos[rglob];
            bool prow = ((unsigned)(fprow - rowB0) < 256u);
            float s = 0.f;
#pragma unroll
            for (int nt = 0; nt < 4; ++nt) {
                float Sv = (acc[mt][nt][rr] + 1.f) * (0.5f * TAU);
                if (prow && rowB0 + cloc[nt] == fprow) posv[rglob] = Sv;
                s += (ycol[nt] != yrow) ? __expf(Sv) : 0.f;
            }
            s += __shfl_xor(s, 1, 16);
            s += __shfl_xor(s, 2, 16);
            s += __shfl_xor(s, 4, 16);
            s += __shfl_xor(s, 8, 16);
            if (lc == 0) atomicAdd(&rowsum[rglob], s);
        }
    }
}

// K3: single block; lse_i = log(rowsum_i + exp(pv_i) + (N-2+cnt)); out = mean(lse - pv)
__global__ __launch_bounds__(1024) void k_finalize(const float* __restrict__ rowsum,
                                                   const float* __restrict__ posv,
                                                   const int* __restrict__ y,
                                                   const int* __restrict__ cnt,
                                                   float* __restrict__ out) {
    int t = threadIdx.x;
    float acc = 0.f;
#pragma unroll
    for (int k = 0; k < 4; ++k) {
        int i = t + k * 1024;
        float pv = posv[i];
        float tot = rowsum[i] + __expf(pv) + (float)(NN - 2 + cnt[y[i]]);
        acc += logf(tot) - pv;
    }
#pragma unroll
    for (int m = 1; m < 64; m <<= 1) acc += __shfl_xor(acc, m, 64);
    __shared__ float wsum[16];
    int w = t >> 6, lane = t & 63;
    if (lane == 0) wsum[w] = acc;
    __syncthreads();
    if (t == 0) {
        float s = 0.f;
#pragma unroll
        for (int q = 0; q < 16; ++q) s += wsum[q];
        *out = s / (float)NN;
    }
}

extern "C" void kernel_launch(void* const* d_in, const int* in_sizes, int n_in,
                              void* d_out, int out_size, void* d_ws, size_t ws_size,
                              hipStream_t stream) {
    const float* X = (const float*)d_in[0];
    const int* y = (const int*)d_in[1];
    float* out = (float*)d_out;

    char* ws = (char*)d_ws;
    bf16* Xn    = (bf16*)ws;                                   // 8 MB
    float* rsum = (float*)(ws + 8 * 1024 * 1024);              // 16 KB
    float* posv = (float*)(ws + 8 * 1024 * 1024 + 16 * 1024);  // 16 KB
    int* cnt    = (int*)(ws + 8 * 1024 * 1024 + 32 * 1024);    // 512 B
    int* fpos   = (int*)(ws + 8 * 1024 * 1024 + 36 * 1024);    // 16 KB

    k_prep<<<dim3(NN / 4 + 1), 256, 0, stream>>>(X, y, Xn, rsum, posv, cnt, fpos);
    k_gemm<<<dim3(NB_GEMM), 512, 0, stream>>>(Xn, y, fpos, rsum, posv);
    k_finalize<<<dim3(1), 1024, 0, stream>>>(rsum, posv, y, cnt, out);
}

// Round 9
// 124.811 us; speedup vs baseline: 1.1019x; 1.0122x over previous
//
#include <hip/hip_runtime.h>
#include <hip/hip_bf16.h>
#include <math.h>

#define NN 4096
#define DD 1024
#define NCLS 128
#define TAU 0.5f
#define EPSV 1e-8f
#define NB_GEMM 2080   // 64*65/2 upper-triangle 64x64 tiles; 2080 = 8 XCDs * 260
#define NT 32          // K-steps (DD / 32)

typedef __bf16 bf16;
typedef __bf16 bf16x8 __attribute__((ext_vector_type(8)));
typedef __bf16 bf16x4 __attribute__((ext_vector_type(4)));
typedef float f32x4 __attribute__((ext_vector_type(4)));

__device__ __forceinline__ void gl2lds16(const void* g, void* l) {
    __builtin_amdgcn_global_load_lds(
        (const __attribute__((address_space(1))) void*)g,
        (__attribute__((address_space(3))) void*)l,
        16, 0, 0);
}

// K1: block 0 = class stats -> per-row first-pos index fpos[i];
//     blocks 1..NN/4 = per-row L2 norm -> normalized bf16 copy, zero rowsum/posv.
__global__ __launch_bounds__(256) void k_prep(const float* __restrict__ X,
                                              const int* __restrict__ y,
                                              bf16* __restrict__ Xn,
                                              float* __restrict__ rsum,
                                              float* __restrict__ posv,
                                              int* __restrict__ cnt,
                                              int* __restrict__ fpos) {
    const int t = threadIdx.x;
    if (blockIdx.x == 0) {
        __shared__ int sc[NCLS], s1[NCLS], s2[NCLS];
        if (t < NCLS) { sc[t] = 0; s1[t] = 0x7fffffff; s2[t] = 0x7fffffff; }
        __syncthreads();
        int yv[16];
#pragma unroll
        for (int k = 0; k < 16; ++k) {
            int i = t + k * 256;
            yv[k] = y[i];
            atomicAdd(&sc[yv[k]], 1);
            atomicMin(&s1[yv[k]], i);
        }
        __syncthreads();
#pragma unroll
        for (int k = 0; k < 16; ++k) {
            int i = t + k * 256;
            if (s1[yv[k]] != i) atomicMin(&s2[yv[k]], i);
        }
        __syncthreads();
#pragma unroll
        for (int k = 0; k < 16; ++k) {
            int i = t + k * 256;
            int c = yv[k];
            fpos[i] = (sc[c] >= 2) ? (s1[c] == i ? s2[c] : s1[c]) : -1;
        }
        if (t < NCLS) cnt[t] = sc[t];
        return;
    }
    const int w = t >> 6, lane = t & 63;
    const int row = (blockIdx.x - 1) * 4 + w;
    const float* xr = X + (size_t)row * DD;
    float4 v[4];
    float ss = 0.f;
#pragma unroll
    for (int c = 0; c < 4; ++c) {
        v[c] = *(const float4*)(xr + c * 256 + lane * 4);
        ss += v[c].x * v[c].x + v[c].y * v[c].y + v[c].z * v[c].z + v[c].w * v[c].w;
    }
#pragma unroll
    for (int m = 1; m < 64; m <<= 1) ss += __shfl_xor(ss, m, 64);
    float rn = 1.f / fmaxf(sqrtf(ss), EPSV);
    if (lane == 0) { rsum[row] = 0.f; posv[row] = 0.f; }
#pragma unroll
    for (int c = 0; c < 4; ++c) {
        bf16x4 o;
        o.x = (bf16)(v[c].x * rn);
        o.y = (bf16)(v[c].y * rn);
        o.z = (bf16)(v[c].z * rn);
        o.w = (bf16)(v[c].w * rn);
        *(bf16x4*)(Xn + (size_t)row * DD + c * 256 + lane * 4) = o;
    }
}

// K2: SINGLE-WAVE 64x64-tile upper-triangle bf16 MFMA gram.
// R8 post-mortem: barrier-lockstep + depth-1 prefetch exposes ~1300 cyc/step
// (m233's stage+drain = 72% reproduced). Fix: 64-thread blocks -> NO barriers
// exist; ordering is wave-local s_waitcnt only. 2080 blocks (8.1/CU, full
// residency at 16 KB LDS), acc[4][4] = 16 MFMA/step/wave (m97's proven shape),
// counted vmcnt(8) = next tile's 8 loads stay in flight, never drain mid-loop.
// lgkmcnt(0) before stage makes buffer-overwrite airtight (all ds_reads of the
// target buffer have returned before the overwriting loads are issued).
// NO device-scope fences (round-1 lesson: per-block L2 wb/inv -> 93us).
__global__ __launch_bounds__(64, 3) void k_gemm(const bf16* __restrict__ Xn,
                                                const int* __restrict__ y,
                                                const int* __restrict__ fpos,
                                                float* __restrict__ rowsum,
                                                float* __restrict__ posv) {
    __shared__ __align__(16) bf16 As[2][64 * 32];   // 2 x 4 KB
    __shared__ __align__(16) bf16 Bs[2][64 * 32];   // 2 x 4 KB  (16 KB total)

    // bijective XCD swizzle: 2080 = 8 * 260
    int id = (blockIdx.x & 7) * 260 + (blockIdx.x >> 3);
    // decode linear id -> (bi, bj), bi <= bj
    float ff = sqrtf((float)(8 * id + 1));
    int bj = (int)((ff - 1.f) * 0.5f);
    if (bj * (bj + 1) / 2 > id) bj--;
    if ((bj + 1) * (bj + 2) / 2 <= id) bj++;
    int bi = id - bj * (bj + 1) / 2;
    const int rowA0 = bi * 64;
    const int rowB0 = bj * 64;
    const bool diag = (bi == bj);

    const int lane = threadIdx.x;        // 64 threads = 1 wave
    const int lr = lane >> 4, lc = lane & 15;
    const int sw = (lc >> 1) & 3;        // read-side k-slot swizzle inverse

    f32x4 acc[4][4];
#pragma unroll
    for (int i = 0; i < 4; ++i)
#pragma unroll
        for (int j = 0; j < 4; ++j) acc[i][j] = (f32x4){0.f, 0.f, 0.f, 0.f};

    // staging: instr j covers rows j*16+(lane>>2), k-slot lane&3 of a [64][32]
    // tile. k-slot XOR swizzle kg = g ^ ((row>>1)&3); since (j*16+r)>>1 & 3 ==
    // (r>>1)&3, one kg per thread serves all 4 instructions.
    const int r = lane >> 2;             // 0..15
    const int g = lane & 3;
    const int kg = g ^ ((r >> 1) & 3);
    const bf16* gA = Xn + (size_t)(rowA0 + r) * DD + kg * 8;
    const bf16* gB = Xn + (size_t)(rowB0 + r) * DD + kg * 8;

    auto stage = [&](int buf, int k0) {
#pragma unroll
        for (int j = 0; j < 4; ++j) {
            gl2lds16(gA + (size_t)j * 16 * DD + k0, &As[buf][j * 512]);
            gl2lds16(gB + (size_t)j * 16 * DD + k0, &Bs[buf][j * 512]);
        }
    };
    auto compute = [&](int buf) {
        bf16x8 af[4], bfr[4];
#pragma unroll
        for (int mt = 0; mt < 4; ++mt)
            af[mt] = *(const bf16x8*)(&As[buf][(mt * 16 + lc) * 32 + ((lr ^ sw) * 8)]);
#pragma unroll
        for (int nt = 0; nt < 4; ++nt)
            bfr[nt] = *(const bf16x8*)(&Bs[buf][(nt * 16 + lc) * 32 + ((lr ^ sw) * 8)]);
#pragma unroll
        for (int mt = 0; mt < 4; ++mt)
#pragma unroll
            for (int nt = 0; nt < 4; ++nt)
                acc[mt][nt] = __builtin_amdgcn_mfma_f32_16x16x32_bf16(
                    af[mt], bfr[nt], acc[mt][nt], 0, 0, 0);
    };

    // prologue: stage tile 0 (8 loads in flight)
    stage(0, 0);

    // main loop: no barriers (single wave). lgkmcnt(0) -> my reads of the
    // buffer being overwritten are done; stage(t+1); vmcnt(8) -> tile t's 8
    // loads landed (t+1's 8 still in flight); compute.
#pragma unroll 2
    for (int t = 0; t < NT - 1; ++t) {
        asm volatile("s_waitcnt lgkmcnt(0)" ::: "memory");
        stage((t + 1) & 1, (t + 1) * 32);
        asm volatile("s_waitcnt vmcnt(8)" ::: "memory");
        compute(t & 1);
    }
    asm volatile("s_waitcnt vmcnt(0)" ::: "memory");
    compute((NT - 1) & 1);

    // Epilogue: S=(c+1)*0.25; mask same-class (diag cell auto-masked: same y);
    // row-reduce always; col-reduce only off-diag (each unordered pair covered
    // once). posv where (row,col)=(i,fp(i)). y/fpos direct reads (L2-hot).
    int cloc[4], ycol[4], fcol[4];
    bool pcol[4];
#pragma unroll
    for (int nt = 0; nt < 4; ++nt) {
        cloc[nt] = nt * 16 + lc;
        ycol[nt] = y[rowB0 + cloc[nt]];
        fcol[nt] = fpos[rowB0 + cloc[nt]];
        pcol[nt] = ((unsigned)(fcol[nt] - rowA0) < 64u);
    }
    float colacc[4] = {0.f, 0.f, 0.f, 0.f};
#pragma unroll
    for (int mt = 0; mt < 4; ++mt) {
#pragma unroll
        for (int rr = 0; rr < 4; ++rr) {
            int rloc = mt * 16 + lr * 4 + rr;   // C row = (lane>>4)*4+reg
            int rglob = rowA0 + rloc;
            int yrow = y[rglob];
            int fprow = fpos[rglob];
            bool prow = ((unsigned)(fprow - rowB0) < 64u);
            float s = 0.f;
#pragma unroll
            for (int nt = 0; nt < 4; ++nt) {
                float Sv = (acc[mt][nt][rr] + 1.f) * (0.5f * TAU);
                int cg = rowB0 + cloc[nt];
                if (prow && cg == fprow) posv[rglob] = Sv;
                if (pcol[nt] && fcol[nt] == rglob) posv[cg] = Sv;
                float e = (ycol[nt] != yrow) ? __expf(Sv) : 0.f;
                s += e;
                colacc[nt] += e;
            }
            s += __shfl_xor(s, 1, 16);
            s += __shfl_xor(s, 2, 16);
            s += __shfl_xor(s, 4, 16);
            s += __shfl_xor(s, 8, 16);
            if (lc == 0) atomicAdd(&rowsum[rglob], s);
        }
    }
    if (!diag) {
#pragma unroll
        for (int nt = 0; nt < 4; ++nt) {
            float cs = colacc[nt];
            cs += __shfl_xor(cs, 16, 64);
            cs += __shfl_xor(cs, 32, 64);
            if (lane < 16) atomicAdd(&rowsum[rowB0 + nt * 16 + lane], cs);
        }
    }
}

// K3: single block; lse_i = log(rowsum_i + exp(pv_i) + (N-2+cnt)); out = mean(lse - pv)
__global__ __launch_bounds__(1024) void k_finalize(const float* __restrict__ rowsum,
                                                   const float* __restrict__ posv,
                                                   const int* __restrict__ y,
                                                   const int* __restrict__ cnt,
                                                   float* __restrict__ out) {
    int t = threadIdx.x;
    float acc = 0.f;
#pragma unroll
    for (int k = 0; k < 4; ++k) {
        int i = t + k * 1024;
        float pv = posv[i];
        float tot = rowsum[i] + __expf(pv) + (float)(NN - 2 + cnt[y[i]]);
        acc += logf(tot) - pv;
    }
#pragma unroll
    for (int m = 1; m < 64; m <<= 1) acc += __shfl_xor(acc, m, 64);
    __shared__ float wsum[16];
    int w = t >> 6, lane = t & 63;
    if (lane == 0) wsum[w] = acc;
    __syncthreads();
    if (t == 0) {
        float s = 0.f;
#pragma unroll
        for (int q = 0; q < 16; ++q) s += wsum[q];
        *out = s / (float)NN;
    }
}

extern "C" void kernel_launch(void* const* d_in, const int* in_sizes, int n_in,
                              void* d_out, int out_size, void* d_ws, size_t ws_size,
                              hipStream_t stream) {
    const float* X = (const float*)d_in[0];
    const int* y = (const int*)d_in[1];
    float* out = (float*)d_out;

    char* ws = (char*)d_ws;
    bf16* Xn    = (bf16*)ws;                                   // 8 MB
    float* rsum = (float*)(ws + 8 * 1024 * 1024);              // 16 KB
    float* posv = (float*)(ws + 8 * 1024 * 1024 + 16 * 1024);  // 16 KB
    int* cnt    = (int*)(ws + 8 * 1024 * 1024 + 32 * 1024);    // 512 B
    int* fpos   = (int*)(ws + 8 * 1024 * 1024 + 36 * 1024);    // 16 KB

    k_prep<<<dim3(NN / 4 + 1), 256, 0, stream>>>(X, y, Xn, rsum, posv, cnt, fpos);
    k_gemm<<<dim3(NB_GEMM), 64, 0, stream>>>(Xn, y, fpos, rsum, posv);
    k_finalize<<<dim3(1), 1024, 0, stream>>>(rsum, posv, y, cnt, out);
}